// Round 1
// baseline (1358.188 us; speedup 1.0000x reference)
//
#include <hip/hip_runtime.h>
#include <math.h>

// Problem constants
#define A_N   128
#define NLAT  16
#define LDIM  256
#define DEPTH 4
#define SHN   8
#define SHD_  32
#define FFD   256
#define FLATD 4096
#define MROWS 2048   // A_N * NLAT

// ---------------------------------------------------------------------------
// copy z -> z_prior (output chunk 1) and zc (workspace), float4 vectorized
// grid: 524288/4/256 = 512 blocks x 256
__global__ void k_copy_z(const float* __restrict__ z,
                         float* __restrict__ zprior,
                         float* __restrict__ zc) {
    int i = blockIdx.x * blockDim.x + threadIdx.x;
    float4 v = ((const float4*)z)[i];
    ((float4*)zprior)[i] = v;
    ((float4*)zc)[i] = v;
}

// ---------------------------------------------------------------------------
// Generic fp32 GEMM: C[M,N] = A[M,K] @ B[N,K]^T  (+bias) (+relu)
// Up to 3 weight/bias/out sets selected by blockIdx.z (fused qkv launches).
// grid: (N/64, M/64, nmat); block 256 (16x16), 4x4 microtile, BK=16.
// mode: 0 = none, 1 = +bias, 2 = +bias+relu
__global__ void k_gemm_bt(const float* __restrict__ Ap,
                          const float* __restrict__ B0, const float* __restrict__ B1,
                          const float* __restrict__ B2,
                          const float* __restrict__ d0, const float* __restrict__ d1,
                          const float* __restrict__ d2,
                          float* __restrict__ C0, float* __restrict__ C1,
                          float* __restrict__ C2,
                          int M, int N, int K, int mode) {
    const float* B; const float* bias; float* C;
    if (blockIdx.z == 0)      { B = B0; bias = d0; C = C0; }
    else if (blockIdx.z == 1) { B = B1; bias = d1; C = C1; }
    else                      { B = B2; bias = d2; C = C2; }

    __shared__ float As[64][17];   // +1 pad: kills the stride-64 bank conflicts
    __shared__ float Bs[64][17];

    const int tid = threadIdx.x;
    const int tx = tid & 15, ty = tid >> 4;
    const int m0 = blockIdx.y * 64, n0 = blockIdx.x * 64;

    float acc[4][4] = {};

    for (int k0 = 0; k0 < K; k0 += 16) {
#pragma unroll
        for (int l = 0; l < 4; ++l) {
            int idx = tid + l * 256;          // 0..1023 covers 64x16 tile
            int r = idx >> 4, c = idx & 15;
            As[r][c] = Ap[(size_t)(m0 + r) * K + (k0 + c)];
            Bs[r][c] = B [(size_t)(n0 + r) * K + (k0 + c)];
        }
        __syncthreads();
#pragma unroll
        for (int kk = 0; kk < 16; ++kk) {
            float a[4], b[4];
#pragma unroll
            for (int i = 0; i < 4; ++i) a[i] = As[ty * 4 + i][kk];
#pragma unroll
            for (int j = 0; j < 4; ++j) b[j] = Bs[tx * 4 + j][kk];
#pragma unroll
            for (int i = 0; i < 4; ++i)
#pragma unroll
                for (int j = 0; j < 4; ++j)
                    acc[i][j] += a[i] * b[j];
        }
        __syncthreads();
    }

#pragma unroll
    for (int i = 0; i < 4; ++i) {
        int m = m0 + ty * 4 + i;
#pragma unroll
        for (int j = 0; j < 4; ++j) {
            int n = n0 + tx * 4 + j;
            float v = acc[i][j];
            if (mode >= 1) v += bias[n];
            if (mode == 2) v = fmaxf(v, 0.0f);
            C[(size_t)m * N + n] = v;
        }
    }
}

// ---------------------------------------------------------------------------
// Latent self-attention: seq=16, heads=8, hd=32 per asset.
// grid: A_N*SHN = 1024 blocks; block 256.
__global__ void k_self_attn(const float* __restrict__ Q,
                            const float* __restrict__ Kp,
                            const float* __restrict__ Vp,
                            float* __restrict__ O) {
    const int a = blockIdx.x >> 3;
    const int h = blockIdx.x & 7;
    __shared__ float qs[16][32], ks[16][32], vs[16][32], ps[16][16];

    const int tid = threadIdx.x;
    for (int idx = tid; idx < 512; idx += 256) {
        int s = idx >> 5, d = idx & 31;
        size_t off = (size_t)(a * 16 + s) * LDIM + h * 32 + d;
        qs[s][d] = Q[off]; ks[s][d] = Kp[off]; vs[s][d] = Vp[off];
    }
    __syncthreads();

    // scores: one (i,j) per thread
    const int i = tid >> 4, j = tid & 15;
    float sc = 0.0f;
#pragma unroll
    for (int d = 0; d < 32; ++d) sc += qs[i][d] * ks[j][d];
    sc *= 0.17677669529663687f;  // 32^-0.5

    // softmax over j: each row lives in a contiguous 16-lane group
    float mx = sc;
#pragma unroll
    for (int m = 8; m; m >>= 1) mx = fmaxf(mx, __shfl_xor(mx, m, 16));
    float e = __expf(sc - mx);
    float sum = e;
#pragma unroll
    for (int m = 8; m; m >>= 1) sum += __shfl_xor(sum, m, 16);
    ps[i][j] = e / sum;
    __syncthreads();

    // O = P @ V
    for (int idx = tid; idx < 512; idx += 256) {
        int s = idx >> 5, d = idx & 31;
        float acc = 0.0f;
#pragma unroll
        for (int jj = 0; jj < 16; ++jj) acc += ps[s][jj] * vs[jj][d];
        O[(size_t)(a * 16 + s) * LDIM + h * 32 + d] = acc;
    }
}

// ---------------------------------------------------------------------------
// out = LN(X + Y) * g + b   row-wise over 256 cols. grid: rows; block 256.
// In-place safe for X==out (each thread reads its element before any write).
__global__ void k_resid_ln(const float* __restrict__ X,
                           const float* __restrict__ Y,
                           const float* __restrict__ g,
                           const float* __restrict__ b,
                           float* __restrict__ out) {
    const int row = blockIdx.x;
    const int c = threadIdx.x;
    float t = X[(size_t)row * LDIM + c] + Y[(size_t)row * LDIM + c];

    float2 v = make_float2(t, t * t);
#pragma unroll
    for (int o = 32; o; o >>= 1) {
        v.x += __shfl_down(v.x, o);
        v.y += __shfl_down(v.y, o);
    }
    __shared__ float2 wred[4];
    __shared__ float2 tot;
    if ((c & 63) == 0) wred[c >> 6] = v;
    __syncthreads();
    if (c == 0) {
        float2 s = make_float2(0.f, 0.f);
        for (int i = 0; i < 4; ++i) { s.x += wred[i].x; s.y += wred[i].y; }
        tot = s;
    }
    __syncthreads();
    float mean = tot.x * (1.0f / 256.0f);
    float var  = tot.y * (1.0f / 256.0f) - mean * mean;
    out[(size_t)row * LDIM + c] = (t - mean) * rsqrtf(var + 1e-5f) * g[c] + b[c];
}

// ---------------------------------------------------------------------------
// CANN scores + softmax: P[i][j] = softmax_j(Q[i]·K[j] / 16)
// grid: 128 blocks (one per i); block 128 (one j per thread).
__global__ void k_cann_scores(const float* __restrict__ Q,
                              const float* __restrict__ Kp,
                              float* __restrict__ P) {
    const int i = blockIdx.x;
    const int j = threadIdx.x;
    __shared__ float qrow[FLATD];
    for (int idx = j; idx < FLATD; idx += 128) qrow[idx] = Q[(size_t)i * FLATD + idx];
    __syncthreads();

    const float4* k4 = (const float4*)(Kp + (size_t)j * FLATD);
    const float4* q4 = (const float4*)qrow;
    float sc = 0.0f;
    for (int t = 0; t < FLATD / 4; ++t) {
        float4 kv = k4[t], qv = q4[t];
        sc += qv.x * kv.x + qv.y * kv.y + qv.z * kv.z + qv.w * kv.w;
    }
    sc *= 0.0625f;  // 256^-0.5

    __shared__ float wtmp[2];
    float mx = sc;
#pragma unroll
    for (int o = 32; o; o >>= 1) mx = fmaxf(mx, __shfl_xor(mx, o));
    if ((j & 63) == 0) wtmp[j >> 6] = mx;
    __syncthreads();
    mx = fmaxf(wtmp[0], wtmp[1]);
    __syncthreads();

    float e = __expf(sc - mx);
    float sum = e;
#pragma unroll
    for (int o = 32; o; o >>= 1) sum += __shfl_xor(sum, o);
    __shared__ float wsum[2];
    if ((j & 63) == 0) wsum[j >> 6] = sum;
    __syncthreads();
    sum = wsum[0] + wsum[1];

    P[(size_t)i * 128 + j] = e / sum;
}

// ---------------------------------------------------------------------------
// H[i][n] = sum_j P[i][j] * V[j][n].  grid: (FLAT/256, 128); block 256.
__global__ void k_cann_out(const float* __restrict__ P,
                           const float* __restrict__ V,
                           float* __restrict__ H) {
    const int i = blockIdx.y;
    const int n = blockIdx.x * 256 + threadIdx.x;
    __shared__ float prow[128];
    if (threadIdx.x < 128) prow[threadIdx.x] = P[(size_t)i * 128 + threadIdx.x];
    __syncthreads();
    float acc = 0.0f;
#pragma unroll 8
    for (int j = 0; j < 128; ++j) acc += prow[j] * V[(size_t)j * FLATD + n];
    H[(size_t)i * FLATD + n] = acc;
}

// ---------------------------------------------------------------------------
extern "C" void kernel_launch(void* const* d_in, const int* in_sizes, int n_in,
                              void* d_out, int out_size, void* d_ws, size_t ws_size,
                              hipStream_t stream) {
    (void)in_sizes; (void)n_in; (void)out_size; (void)ws_size;

    const float* z      = (const float*)d_in[1];
    const float* s_wq   = (const float*)d_in[15];
    const float* s_wk   = (const float*)d_in[16];
    const float* s_wv   = (const float*)d_in[17];
    const float* s_wo   = (const float*)d_in[18];
    const float* s_bo   = (const float*)d_in[19];
    const float* s_ln1g = (const float*)d_in[20];
    const float* s_ln1b = (const float*)d_in[21];
    const float* s_fw1  = (const float*)d_in[22];
    const float* s_fb1  = (const float*)d_in[23];
    const float* s_fw2  = (const float*)d_in[24];
    const float* s_fb2  = (const float*)d_in[25];
    const float* s_ln2g = (const float*)d_in[26];
    const float* s_ln2b = (const float*)d_in[27];
    const float* q_w    = (const float*)d_in[28];
    const float* q_b    = (const float*)d_in[29];
    const float* k_w    = (const float*)d_in[30];
    const float* k_b    = (const float*)d_in[31];
    const float* v_w    = (const float*)d_in[32];
    const float* v_b    = (const float*)d_in[33];

    float* out    = (float*)d_out;
    float* Hout   = out;                 // (A, NL, LD) flattened
    float* Zprior = out + 524288;        // second tuple element

    float* ws = (float*)d_ws;
    const size_t SZ = 524288;            // A*NL*LD
    float* ZC = ws;
    float* Qb = ws + 1 * SZ;
    float* Kb = ws + 2 * SZ;
    float* Vb = ws + 3 * SZ;
    float* T0 = ws + 4 * SZ;
    float* T1 = ws + 5 * SZ;

    k_copy_z<<<512, 256, 0, stream>>>(z, Zprior, ZC);

    for (int i = 0; i < DEPTH; ++i) {
        const float* wq  = s_wq  + (size_t)i * 65536;
        const float* wk  = s_wk  + (size_t)i * 65536;
        const float* wv  = s_wv  + (size_t)i * 65536;
        const float* wo  = s_wo  + (size_t)i * 65536;
        const float* bo  = s_bo  + (size_t)i * 256;
        const float* g1  = s_ln1g + (size_t)i * 256;
        const float* b1  = s_ln1b + (size_t)i * 256;
        const float* fw1 = s_fw1 + (size_t)i * 65536;
        const float* fb1 = s_fb1 + (size_t)i * 256;
        const float* fw2 = s_fw2 + (size_t)i * 65536;
        const float* fb2 = s_fb2 + (size_t)i * 256;
        const float* g2  = s_ln2g + (size_t)i * 256;
        const float* b2  = s_ln2b + (size_t)i * 256;

        // fused q,k,v projections (no bias in reference _attn projections)
        dim3 g3(256 / 64, MROWS / 64, 3);
        k_gemm_bt<<<g3, 256, 0, stream>>>(ZC, wq, wk, wv,
                                          nullptr, nullptr, nullptr,
                                          Qb, Kb, Vb, MROWS, 256, 256, 0);
        k_self_attn<<<1024, 256, 0, stream>>>(Qb, Kb, Vb, T0);

        dim3 g1d(256 / 64, MROWS / 64, 1);
        k_gemm_bt<<<g1d, 256, 0, stream>>>(T0, wo, wo, wo, bo, bo, bo,
                                           T1, T1, T1, MROWS, 256, 256, 1);
        k_resid_ln<<<MROWS, 256, 0, stream>>>(ZC, T1, g1, b1, ZC);

        k_gemm_bt<<<g1d, 256, 0, stream>>>(ZC, fw1, fw1, fw1, fb1, fb1, fb1,
                                           T0, T0, T0, MROWS, 256, 256, 2);
        k_gemm_bt<<<g1d, 256, 0, stream>>>(T0, fw2, fw2, fw2, fb2, fb2, fb2,
                                           T1, T1, T1, MROWS, 256, 256, 1);
        k_resid_ln<<<MROWS, 256, 0, stream>>>(ZC, T1, g2, b2, ZC);
    }

    // CANN: q/k/v = zf @ W^T + b   (M=128, N=4096, K=4096, fused x3)
    dim3 gc(FLATD / 64, A_N / 64, 3);
    k_gemm_bt<<<gc, 256, 0, stream>>>(ZC, q_w, k_w, v_w, q_b, k_b, v_b,
                                      Qb, Kb, Vb, A_N, FLATD, FLATD, 1);
    k_cann_scores<<<A_N, 128, 0, stream>>>(Qb, Kb, T0);
    k_cann_out<<<dim3(FLATD / 256, A_N), 256, 0, stream>>>(T0, Vb, Hout);
}

// Round 3
// 657.919 us; speedup vs baseline: 2.0644x; 2.0644x over previous
//
#include <hip/hip_runtime.h>
#include <math.h>

typedef __bf16 bf16x8 __attribute__((ext_vector_type(8)));
typedef float  f32x4  __attribute__((ext_vector_type(4)));

#define MFMA(a,b,c) __builtin_amdgcn_mfma_f32_16x16x32_bf16((a),(b),(c),0,0,0)

#define A_N   128
#define LDIM  256
#define FLATD 4096

// ---------------------------------------------------------------------------
// Convert the 6 latent weight arrays (each [4][256][256] fp32) to split bf16
// (hi + lo, lo = bf16(x - fp32(hi))). grid (128, 6) x 256; 8 elems/thread.
__global__ void k_cvt_w(const float* __restrict__ s0, const float* __restrict__ s1,
                        const float* __restrict__ s2, const float* __restrict__ s3,
                        const float* __restrict__ s4, const float* __restrict__ s5,
                        __bf16* __restrict__ dh, __bf16* __restrict__ dl) {
    const float* s;
    switch (blockIdx.y) {
        case 0: s = s0; break; case 1: s = s1; break; case 2: s = s2; break;
        case 3: s = s3; break; case 4: s = s4; break; default: s = s5; break;
    }
    size_t off  = (size_t)blockIdx.x * 2048 + threadIdx.x * 8;
    const float4* sp = (const float4*)(s + off);
    float4 x = sp[0], y = sp[1];
    float v[8] = {x.x, x.y, x.z, x.w, y.x, y.y, y.z, y.w};
    bf16x8 h, l;
    #pragma unroll
    for (int j = 0; j < 8; ++j) {
        __bf16 hh = (__bf16)v[j];
        h[j] = hh;
        l[j] = (__bf16)(v[j] - (float)hh);
    }
    size_t dst = (size_t)blockIdx.y * 262144 + off;
    *(bf16x8*)(dh + dst) = h;
    *(bf16x8*)(dl + dst) = l;
}

// ---------------------------------------------------------------------------
// Fused 4-layer latent transformer, split-bf16 (near-fp32) projections.
// One block per asset (16 rows x 256). 512 threads = 8 waves = 8 heads.
// MFMA 16x16x32 bf16 layouts (verified m89/m91):
//   A[m=lane&15][k=(lane>>4)*8+j], B[n=lane&15][k=(lane>>4)*8+j]
//   C[m=(lane>>4)*4+reg][n=lane&15]
__global__ __launch_bounds__(512) void k_latent(
    const float* __restrict__ z,
    const __bf16* __restrict__ Wh, const __bf16* __restrict__ Wl,
    const float* __restrict__ boa,
    const float* __restrict__ g1a, const float* __restrict__ b1a,
    const float* __restrict__ fb1a, const float* __restrict__ fb2a,
    const float* __restrict__ g2a, const float* __restrict__ b2a,
    float* __restrict__ zprior, __bf16* __restrict__ Zbh, __bf16* __restrict__ Zbl)
{
    // LDS arena 57856 B. Aliases (barrier-guarded):
    //   Ph  aliases zbh (zb dead between qkv-proj and LN1)
    //   ob  aliases Qh + first 256 B of Kh (dead after scores)
    __shared__ __align__(16) char arena[57856];
    float*  zf  = (float*)arena;                    // [16][256] f32 residual
    __bf16* zbh = (__bf16*)(arena + 16384);         // [16][264]
    __bf16* zbl = (__bf16*)(arena + 24832);         // [16][264]
    __bf16* Ph  = (__bf16*)(arena + 16384);         // [8][16][32] (k-pad 0)
    __bf16* Qh  = (__bf16*)(arena + 33280);         // [8][16][32]
    __bf16* ob  = Qh;                               // [16][264]
    __bf16* Kh  = (__bf16*)(arena + 41472);         // [8][16][32]
    __bf16* Vt  = (__bf16*)(arena + 49664);         // [8][32][16] V^T compact

    const int a    = blockIdx.x;
    const int t    = threadIdx.x;
    const int w    = t >> 6;
    const int lane = t & 63;
    const int q    = lane >> 4;
    const int r    = lane & 15;

    // ---- load z -> zf, zbh/zbl; emit z_prior ----
    {
        const float4* zp = (const float4*)(z + (size_t)a * 4096 + t * 8);
        float4 x = zp[0], y = zp[1];
        float4* pr = (float4*)(zprior + (size_t)a * 4096 + t * 8);
        pr[0] = x; pr[1] = y;
        float v[8] = {x.x, x.y, x.z, x.w, y.x, y.y, y.z, y.w};
        int row = t >> 5, col = (t & 31) * 8;
        float*  zr  = zf  + row * 256 + col;
        __bf16* zh  = zbh + row * 264 + col;
        __bf16* zl  = zbl + row * 264 + col;
        #pragma unroll
        for (int j = 0; j < 8; ++j) {
            zr[j] = v[j];
            __bf16 hh = (__bf16)v[j];
            zh[j] = hh;
            zl[j] = (__bf16)(v[j] - (float)hh);
        }
    }
    __syncthreads();

    auto do_ln = [&](const float* g, const float* bb) {
        int row = t >> 5, sub = t & 31;
        float* zr = zf + row * 256 + sub * 8;
        float v[8], s1 = 0.f, s2 = 0.f;
        #pragma unroll
        for (int j = 0; j < 8; ++j) { v[j] = zr[j]; s1 += v[j]; s2 += v[j]*v[j]; }
        #pragma unroll
        for (int o = 1; o <= 16; o <<= 1) {
            s1 += __shfl_xor(s1, o, 32);
            s2 += __shfl_xor(s2, o, 32);
        }
        float mean = s1 * (1.0f/256.0f);
        float var  = s2 * (1.0f/256.0f) - mean * mean;
        float inv  = rsqrtf(var + 1e-5f);
        __bf16* zh = zbh + row * 264 + sub * 8;
        __bf16* zl = zbl + row * 264 + sub * 8;
        #pragma unroll
        for (int j = 0; j < 8; ++j) {
            float y = (v[j] - mean) * inv * g[sub*8+j] + bb[sub*8+j];
            zr[j] = y;
            __bf16 hh = (__bf16)y;
            zh[j] = hh;
            zl[j] = (__bf16)(y - (float)hh);
        }
    };

    const f32x4 zero4 = {0.f, 0.f, 0.f, 0.f};
    bf16x8 zer8;
    #pragma unroll
    for (int j = 0; j < 8; ++j) zer8[j] = (__bf16)0.0f;

    for (int lp = 0; lp < 4; ++lp) {
        const size_t lo0 = (size_t)lp * 65536;
        const __bf16* wqh = Wh + 0*262144 + lo0; const __bf16* wql = Wl + 0*262144 + lo0;
        const __bf16* wkh = Wh + 1*262144 + lo0; const __bf16* wkl = Wl + 1*262144 + lo0;
        const __bf16* wvh = Wh + 2*262144 + lo0; const __bf16* wvl = Wl + 2*262144 + lo0;
        const __bf16* woh = Wh + 3*262144 + lo0; const __bf16* wol = Wl + 3*262144 + lo0;
        const __bf16* f1h = Wh + 4*262144 + lo0; const __bf16* f1l = Wl + 4*262144 + lo0;
        const __bf16* f2h = Wh + 5*262144 + lo0; const __bf16* f2l = Wl + 5*262144 + lo0;
        const float* bo  = boa  + lp*256;
        const float* g1  = g1a  + lp*256; const float* b1 = b1a + lp*256;
        const float* fb1 = fb1a + lp*256; const float* fb2 = fb2a + lp*256;
        const float* g2  = g2a  + lp*256; const float* b2 = b2a + lp*256;

        // ---- q,k,v projections (split A x split B, 3 products) ----
        {
            bf16x8 afh[8], afl[8];
            #pragma unroll
            for (int ks = 0; ks < 8; ++ks) {
                afh[ks] = *(const bf16x8*)(zbh + r*264 + ks*32 + q*8);
                afl[ks] = *(const bf16x8*)(zbl + r*264 + ks*32 + q*8);
            }
            #pragma unroll
            for (int which = 0; which < 3; ++which) {
                const __bf16* wph = (which == 0) ? wqh : ((which == 1) ? wkh : wvh);
                const __bf16* wpl = (which == 0) ? wql : ((which == 1) ? wkl : wvl);
                #pragma unroll
                for (int nt = 0; nt < 2; ++nt) {
                    int nc = w*32 + nt*16;
                    f32x4 acc = zero4;
                    #pragma unroll
                    for (int ks = 0; ks < 8; ++ks) {
                        size_t woff = (size_t)(nc + r)*256 + ks*32 + q*8;
                        bf16x8 bh = *(const bf16x8*)(wph + woff);
                        bf16x8 bl = *(const bf16x8*)(wpl + woff);
                        acc = MFMA(afh[ks], bh, acc);
                        acc = MFMA(afl[ks], bh, acc);
                        acc = MFMA(afh[ks], bl, acc);
                    }
                    #pragma unroll
                    for (int i = 0; i < 4; ++i) {
                        int mrow = q*4 + i;
                        if (which == 0)      Qh[(w*16 + mrow)*32 + nt*16 + r] = (__bf16)acc[i];
                        else if (which == 1) Kh[(w*16 + mrow)*32 + nt*16 + r] = (__bf16)acc[i];
                        else                 Vt[(w*32 + nt*16 + r)*16 + mrow] = (__bf16)acc[i];
                    }
                }
            }
        }
        __syncthreads();   // Qh/Kh/Vt visible; zb reads done (Ph may alias)

        // ---- scores + softmax, head w per wave ----
        {
            bf16x8 qa = *(const bf16x8*)(Qh + (w*16 + r)*32 + q*8);
            bf16x8 ka = *(const bf16x8*)(Kh + (w*16 + r)*32 + q*8);
            f32x4 s = MFMA(qa, ka, zero4);   // S[i=q*4+reg][j=r], K = hd = 32
            #pragma unroll
            for (int i = 0; i < 4; ++i) {
                float sc = s[i] * 0.17677669529663687f;
                float mx = sc;
                #pragma unroll
                for (int o = 1; o <= 8; o <<= 1) mx = fmaxf(mx, __shfl_xor(mx, o, 16));
                float e = __expf(sc - mx);
                float sm = e;
                #pragma unroll
                for (int o = 1; o <= 8; o <<= 1) sm += __shfl_xor(sm, o, 16);
                Ph[(w*16 + q*4 + i)*32 + r]      = (__bf16)(e / sm);
                Ph[(w*16 + q*4 + i)*32 + 16 + r] = (__bf16)0.0f;   // k-pad
            }
        }
        __syncthreads();   // all Qh/Kh reads done (ob may alias)

        // ---- O = P @ V.  B rows k>=16 forced zero in registers ----
        {
            bf16x8 pa = *(const bf16x8*)(Ph + (w*16 + r)*32 + q*8);
            #pragma unroll
            for (int nt = 0; nt < 2; ++nt) {
                bf16x8 vb = (q < 2)
                    ? *(const bf16x8*)(Vt + (w*32 + nt*16 + r)*16 + q*8) : zer8;
                f32x4 o = MFMA(pa, vb, zero4);   // O[i=q*4+reg][d=nt*16+r]
                #pragma unroll
                for (int i = 0; i < 4; ++i)
                    ob[(q*4 + i)*264 + w*32 + nt*16 + r] = (__bf16)o[i];
            }
        }
        __syncthreads();

        // ---- wo projection (A=ob single, split B) + bias + residual ----
        {
            bf16x8 af[8];
            #pragma unroll
            for (int ks = 0; ks < 8; ++ks)
                af[ks] = *(const bf16x8*)(ob + r*264 + ks*32 + q*8);
            #pragma unroll
            for (int nt = 0; nt < 2; ++nt) {
                int nc = w*32 + nt*16;
                f32x4 acc = zero4;
                #pragma unroll
                for (int ks = 0; ks < 8; ++ks) {
                    size_t woff = (size_t)(nc + r)*256 + ks*32 + q*8;
                    acc = MFMA(af[ks], *(const bf16x8*)(woh + woff), acc);
                    acc = MFMA(af[ks], *(const bf16x8*)(wol + woff), acc);
                }
                #pragma unroll
                for (int i = 0; i < 4; ++i) {
                    int row = q*4 + i, col = nc + r;
                    zf[row*256 + col] = acc[i] + bo[col] + zf[row*256 + col];
                }
            }
        }
        __syncthreads();
        do_ln(g1, b1);
        __syncthreads();

        // ---- FF1: relu(z @ f1^T + fb1) -> ob (split A x split B) ----
        {
            bf16x8 afh[8], afl[8];
            #pragma unroll
            for (int ks = 0; ks < 8; ++ks) {
                afh[ks] = *(const bf16x8*)(zbh + r*264 + ks*32 + q*8);
                afl[ks] = *(const bf16x8*)(zbl + r*264 + ks*32 + q*8);
            }
            #pragma unroll
            for (int nt = 0; nt < 2; ++nt) {
                int nc = w*32 + nt*16;
                f32x4 acc = zero4;
                #pragma unroll
                for (int ks = 0; ks < 8; ++ks) {
                    size_t woff = (size_t)(nc + r)*256 + ks*32 + q*8;
                    bf16x8 bh = *(const bf16x8*)(f1h + woff);
                    bf16x8 bl = *(const bf16x8*)(f1l + woff);
                    acc = MFMA(afh[ks], bh, acc);
                    acc = MFMA(afl[ks], bh, acc);
                    acc = MFMA(afh[ks], bl, acc);
                }
                #pragma unroll
                for (int i = 0; i < 4; ++i) {
                    int row = q*4 + i, col = nc + r;
                    ob[row*264 + col] = (__bf16)fmaxf(acc[i] + fb1[col], 0.0f);
                }
            }
        }
        __syncthreads();

        // ---- FF2 (A=ob single, split B) + bias + residual ----
        {
            bf16x8 af[8];
            #pragma unroll
            for (int ks = 0; ks < 8; ++ks)
                af[ks] = *(const bf16x8*)(ob + r*264 + ks*32 + q*8);
            #pragma unroll
            for (int nt = 0; nt < 2; ++nt) {
                int nc = w*32 + nt*16;
                f32x4 acc = zero4;
                #pragma unroll
                for (int ks = 0; ks < 8; ++ks) {
                    size_t woff = (size_t)(nc + r)*256 + ks*32 + q*8;
                    acc = MFMA(af[ks], *(const bf16x8*)(f2h + woff), acc);
                    acc = MFMA(af[ks], *(const bf16x8*)(f2l + woff), acc);
                }
                #pragma unroll
                for (int i = 0; i < 4; ++i) {
                    int row = q*4 + i, col = nc + r;
                    zf[row*256 + col] = acc[i] + fb2[col] + zf[row*256 + col];
                }
            }
        }
        __syncthreads();
        do_ln(g2, b2);
        __syncthreads();
    }

    // ---- emit final z split as bf16 [A_N][4096] for the CANN GEMM ----
    {
        int row = t >> 5, col = (t & 31) * 8;
        *(bf16x8*)(Zbh + (size_t)a * 4096 + row * 256 + col) =
            *(const bf16x8*)(zbh + row * 264 + col);
        *(bf16x8*)(Zbl + (size_t)a * 4096 + row * 256 + col) =
            *(const bf16x8*)(zbl + row * 264 + col);
    }
}

// ---------------------------------------------------------------------------
// CANN q/k/v GEMM, split-bf16: C[128,4096] = Z @ W^T + b, near-fp32 accuracy.
// BM=128 (W read exactly once), BN=32, BK=64. grid (128, 3) x 256 (4 waves).
// A rows padded to 72 bf16 (144 B = 36 dwords -> 2-way LDS aliasing, free).
__global__ __launch_bounds__(256) void k_cann_gemm(
    const __bf16* __restrict__ Zh, const __bf16* __restrict__ Zl,
    const float* __restrict__ W0, const float* __restrict__ W1, const float* __restrict__ W2,
    const float* __restrict__ b0, const float* __restrict__ b1, const float* __restrict__ b2,
    float* __restrict__ C0, float* __restrict__ C1, float* __restrict__ C2)
{
    const float* W; const float* bias; float* C;
    if (blockIdx.y == 0)      { W = W0; bias = b0; C = C0; }
    else if (blockIdx.y == 1) { W = W1; bias = b1; C = C1; }
    else                      { W = W2; bias = b2; C = C2; }

    __shared__ __bf16 Ash[128 * 72];
    __shared__ __bf16 Asl[128 * 72];
    __shared__ __bf16 Bsh[32 * 72];
    __shared__ __bf16 Bsl[32 * 72];

    const int t = threadIdx.x;
    const int w = t >> 6, lane = t & 63, q = lane >> 4, r = lane & 15;
    const int n0 = blockIdx.x * 32;
    const int m0 = w * 32;
    const int br = t >> 3, bc = t & 7;

    const f32x4 zero4 = {0.f, 0.f, 0.f, 0.f};
    f32x4 acc[2][2] = {{zero4, zero4}, {zero4, zero4}};

    for (int k0 = 0; k0 < FLATD; k0 += 64) {
        #pragma unroll
        for (int l = 0; l < 4; ++l) {
            int idx = t + l * 256;
            int rr = idx >> 3, cc = idx & 7;
            *(bf16x8*)(Ash + rr*72 + cc*8) =
                *(const bf16x8*)(Zh + (size_t)rr * FLATD + k0 + cc*8);
            *(bf16x8*)(Asl + rr*72 + cc*8) =
                *(const bf16x8*)(Zl + (size_t)rr * FLATD + k0 + cc*8);
        }
        {   // stage B fp32 -> hi/lo bf16 inline
            const float4* wp = (const float4*)(W + (size_t)(n0 + br) * FLATD + k0 + bc*8);
            float4 x = wp[0], y = wp[1];
            float v[8] = {x.x, x.y, x.z, x.w, y.x, y.y, y.z, y.w};
            bf16x8 h, l;
            #pragma unroll
            for (int j = 0; j < 8; ++j) {
                __bf16 hh = (__bf16)v[j];
                h[j] = hh;
                l[j] = (__bf16)(v[j] - (float)hh);
            }
            *(bf16x8*)(Bsh + br*72 + bc*8) = h;
            *(bf16x8*)(Bsl + br*72 + bc*8) = l;
        }
        __syncthreads();
        #pragma unroll
        for (int ks = 0; ks < 2; ++ks) {
            bf16x8 a0h = *(const bf16x8*)(Ash + (m0 + r)*72      + ks*32 + q*8);
            bf16x8 a1h = *(const bf16x8*)(Ash + (m0 + 16 + r)*72 + ks*32 + q*8);
            bf16x8 a0l = *(const bf16x8*)(Asl + (m0 + r)*72      + ks*32 + q*8);
            bf16x8 a1l = *(const bf16x8*)(Asl + (m0 + 16 + r)*72 + ks*32 + q*8);
            bf16x8 g0h = *(const bf16x8*)(Bsh + r*72             + ks*32 + q*8);
            bf16x8 g1h = *(const bf16x8*)(Bsh + (16 + r)*72      + ks*32 + q*8);
            bf16x8 g0l = *(const bf16x8*)(Bsl + r*72             + ks*32 + q*8);
            bf16x8 g1l = *(const bf16x8*)(Bsl + (16 + r)*72      + ks*32 + q*8);
            acc[0][0] = MFMA(a0h, g0h, acc[0][0]);
            acc[0][0] = MFMA(a0l, g0h, acc[0][0]);
            acc[0][0] = MFMA(a0h, g0l, acc[0][0]);
            acc[0][1] = MFMA(a0h, g1h, acc[0][1]);
            acc[0][1] = MFMA(a0l, g1h, acc[0][1]);
            acc[0][1] = MFMA(a0h, g1l, acc[0][1]);
            acc[1][0] = MFMA(a1h, g0h, acc[1][0]);
            acc[1][0] = MFMA(a1l, g0h, acc[1][0]);
            acc[1][0] = MFMA(a1h, g0l, acc[1][0]);
            acc[1][1] = MFMA(a1h, g1h, acc[1][1]);
            acc[1][1] = MFMA(a1l, g1h, acc[1][1]);
            acc[1][1] = MFMA(a1h, g1l, acc[1][1]);
        }
        __syncthreads();
    }

    #pragma unroll
    for (int mi = 0; mi < 2; ++mi)
        #pragma unroll
        for (int ni = 0; ni < 2; ++ni)
            #pragma unroll
            for (int i = 0; i < 4; ++i) {
                int row = m0 + mi*16 + q*4 + i;
                int col = n0 + ni*16 + r;
                C[(size_t)row * FLATD + col] = acc[mi][ni][i] + bias[col];
            }
}

// ---------------------------------------------------------------------------
// CANN scores + softmax: P[i][j] = softmax_j(Q[i]·K[j] / 16)  (fp32)
__global__ void k_cann_scores(const float* __restrict__ Q,
                              const float* __restrict__ Kp,
                              float* __restrict__ P) {
    const int i = blockIdx.x;
    const int j = threadIdx.x;
    __shared__ float qrow[FLATD];
    for (int idx = j; idx < FLATD; idx += 128) qrow[idx] = Q[(size_t)i * FLATD + idx];
    __syncthreads();

    const float4* k4 = (const float4*)(Kp + (size_t)j * FLATD);
    const float4* q4 = (const float4*)qrow;
    float sc = 0.0f;
    #pragma unroll 8
    for (int tt = 0; tt < FLATD / 4; ++tt) {
        float4 kv = k4[tt], qv = q4[tt];
        sc += qv.x*kv.x + qv.y*kv.y + qv.z*kv.z + qv.w*kv.w;
    }
    sc *= 0.0625f;

    __shared__ float wtmp[2];
    float mx = sc;
    #pragma unroll
    for (int o = 32; o; o >>= 1) mx = fmaxf(mx, __shfl_xor(mx, o));
    if ((j & 63) == 0) wtmp[j >> 6] = mx;
    __syncthreads();
    mx = fmaxf(wtmp[0], wtmp[1]);
    __syncthreads();

    float e = __expf(sc - mx);
    float sum = e;
    #pragma unroll
    for (int o = 32; o; o >>= 1) sum += __shfl_xor(sum, o);
    __shared__ float wsum[2];
    if ((j & 63) == 0) wsum[j >> 6] = sum;
    __syncthreads();
    sum = wsum[0] + wsum[1];

    P[(size_t)i * 128 + j] = e / sum;
}

// ---------------------------------------------------------------------------
// H[i][n] = sum_j P[i][j] * V[j][n]
__global__ void k_cann_out(const float* __restrict__ P,
                           const float* __restrict__ V,
                           float* __restrict__ H) {
    const int i = blockIdx.y;
    const int n = blockIdx.x * 256 + threadIdx.x;
    __shared__ float prow[128];
    if (threadIdx.x < 128) prow[threadIdx.x] = P[(size_t)i * 128 + threadIdx.x];
    __syncthreads();
    float acc = 0.0f;
    #pragma unroll 8
    for (int j = 0; j < 128; ++j) acc += prow[j] * V[(size_t)j * FLATD + n];
    H[(size_t)i * FLATD + n] = acc;
}

// ---------------------------------------------------------------------------
extern "C" void kernel_launch(void* const* d_in, const int* in_sizes, int n_in,
                              void* d_out, int out_size, void* d_ws, size_t ws_size,
                              hipStream_t stream) {
    (void)in_sizes; (void)n_in; (void)out_size; (void)ws_size;

    const float* z      = (const float*)d_in[1];
    const float* s_wq   = (const float*)d_in[15];
    const float* s_wk   = (const float*)d_in[16];
    const float* s_wv   = (const float*)d_in[17];
    const float* s_wo   = (const float*)d_in[18];
    const float* s_bo   = (const float*)d_in[19];
    const float* s_ln1g = (const float*)d_in[20];
    const float* s_ln1b = (const float*)d_in[21];
    const float* s_fw1  = (const float*)d_in[22];
    const float* s_fb1  = (const float*)d_in[23];
    const float* s_fw2  = (const float*)d_in[24];
    const float* s_fb2  = (const float*)d_in[25];
    const float* s_ln2g = (const float*)d_in[26];
    const float* s_ln2b = (const float*)d_in[27];
    const float* q_w    = (const float*)d_in[28];
    const float* q_b    = (const float*)d_in[29];
    const float* k_w    = (const float*)d_in[30];
    const float* k_b    = (const float*)d_in[31];
    const float* v_w    = (const float*)d_in[32];
    const float* v_b    = (const float*)d_in[33];

    float* out    = (float*)d_out;
    float* Hout   = out;
    float* Zprior = out + 524288;

    // Workspace: [0,6MB) = Wh+Wl, later reused as Qb/Kb/Vb (Wh/Wl dead by then)
    char* w8 = (char*)d_ws;
    __bf16* Wh  = (__bf16*)w8;                     // 6*262144 bf16 = 3 MB
    __bf16* Wl  = (__bf16*)(w8 + 3145728);         // 3 MB
    float*  Qb  = (float*)w8;                      // 2 MB (aliases Wh)
    float*  Kb  = (float*)(w8 + 2097152);          // 2 MB
    float*  Vb  = (float*)(w8 + 4194304);          // 2 MB (aliases Wl tail)
    __bf16* Zbh = (__bf16*)(w8 + 6291456);         // 1 MB
    __bf16* Zbl = (__bf16*)(w8 + 7340032);         // 1 MB
    float*  Pm  = (float*)(w8 + 8388608);          // 64 KB

    k_cvt_w<<<dim3(128, 6), 256, 0, stream>>>(s_wq, s_wk, s_wv, s_wo, s_fw1, s_fw2,
                                              Wh, Wl);

    k_latent<<<A_N, 512, 0, stream>>>(z, Wh, Wl, s_bo, s_ln1g, s_ln1b,
                                      s_fb1, s_fb2, s_ln2g, s_ln2b,
                                      Zprior, Zbh, Zbl);

    k_cann_gemm<<<dim3(FLATD / 32, 3), 256, 0, stream>>>(Zbh, Zbl, q_w, k_w, v_w,
                                                         q_b, k_b, v_b, Qb, Kb, Vb);

    k_cann_scores<<<A_N, 128, 0, stream>>>(Qb, Kb, Pm);
    k_cann_out<<<dim3(FLATD / 256, A_N), 256, 0, stream>>>(Pm, Vb, Hout);
}